// Round 11
// baseline (145.874 us; speedup 1.0000x reference)
//
#include <hip/hip_runtime.h>
#include <hip/hip_cooperative_groups.h>

namespace cg = cooperative_groups;

typedef __bf16 bf16x8 __attribute__((ext_vector_type(8)));
typedef float  f32x4  __attribute__((ext_vector_type(4)));

__device__ __forceinline__ unsigned short f2bf(float f) {
    unsigned int u = __float_as_uint(f);
    u += 0x7FFF + ((u >> 16) & 1);          // RNE
    return (unsigned short)(u >> 16);
}

#define GLD_LDS16(gptr, lptr) \
    __builtin_amdgcn_global_load_lds((const __attribute__((address_space(1))) void*)(gptr), \
                                     (__attribute__((address_space(3))) void*)(lptr), 16, 0, 0)

// ---- 64x64-tile bf16 GEMM body (r9-proven): C[m][n] = sum_k A[m][k]*Bt[n][k], K=512.
// EPI=0: Cout=float[M][512] row-major. EPI=1: Cout=bf16 [512][512] transposed (C^T).
template<int EPI>
__device__ __forceinline__ void gemm_tile(const unsigned short* __restrict__ A,
                                          const unsigned short* __restrict__ Bt,
                                          void* __restrict__ Cout,
                                          unsigned short* lds,   // 2*2*4096 ushorts
                                          int bm, int bn)
{
    const int tid  = threadIdx.x;
    const int lane = tid & 63;
    const int w    = tid >> 6;
    const int wm   = w >> 1, wn = w & 1;

    const int srow   = w * 16 + (lane >> 3);
    const int schunk = (lane & 7) ^ (lane >> 3);    // inverse-swizzle on SOURCE
    const unsigned short* gA0 = A  + (size_t)(bm + srow    ) * 512 + schunk * 8;
    const unsigned short* gA1 = A  + (size_t)(bm + srow + 8) * 512 + schunk * 8;
    const unsigned short* gB0 = Bt + (size_t)(bn + srow    ) * 512 + schunk * 8;
    const unsigned short* gB1 = Bt + (size_t)(bn + srow + 8) * 512 + schunk * 8;

    const int arow = lane & 15;
    const int kg   = lane >> 4;
    int offA[2][2], offB[2][2];
    #pragma unroll
    for (int f = 0; f < 2; ++f)
        #pragma unroll
        for (int kk = 0; kk < 2; ++kk) {
            offA[f][kk] = (wm * 32 + f * 16 + arow) * 128 + (((kk * 4 + kg) ^ (arow & 7)) << 4);
            offB[f][kk] = (wn * 32 + f * 16 + arow) * 128 + (((kk * 4 + kg) ^ (arow & 7)) << 4);
        }

    f32x4 acc[2][2] = {};

    auto stage = [&](int buf, int kt) {
        const int k0 = kt * 64;
        unsigned short* la = lds + buf * 8192;
        unsigned short* lb = la + 4096;
        GLD_LDS16(gA0 + k0, la + (w * 16 + 0) * 64);
        GLD_LDS16(gA1 + k0, la + (w * 16 + 8) * 64);
        GLD_LDS16(gB0 + k0, lb + (w * 16 + 0) * 64);
        GLD_LDS16(gB1 + k0, lb + (w * 16 + 8) * 64);
    };

    stage(0, 0);
    asm volatile("s_waitcnt vmcnt(0)" ::: "memory");
    __syncthreads();

    #pragma unroll
    for (int kt = 0; kt < 8; ++kt) {
        const int buf = kt & 1;
        if (kt < 7) stage(buf ^ 1, kt + 1);
        const char* la = (const char*)(lds + buf * 8192);
        const char* lb = la + 8192;
        #pragma unroll
        for (int kk = 0; kk < 2; ++kk) {
            bf16x8 a0 = *(const bf16x8*)(la + offA[0][kk]);
            bf16x8 a1 = *(const bf16x8*)(la + offA[1][kk]);
            bf16x8 b0 = *(const bf16x8*)(lb + offB[0][kk]);
            bf16x8 b1 = *(const bf16x8*)(lb + offB[1][kk]);
            acc[0][0] = __builtin_amdgcn_mfma_f32_16x16x32_bf16(a0, b0, acc[0][0], 0, 0, 0);
            acc[0][1] = __builtin_amdgcn_mfma_f32_16x16x32_bf16(a0, b1, acc[0][1], 0, 0, 0);
            acc[1][0] = __builtin_amdgcn_mfma_f32_16x16x32_bf16(a1, b0, acc[1][0], 0, 0, 0);
            acc[1][1] = __builtin_amdgcn_mfma_f32_16x16x32_bf16(a1, b1, acc[1][1], 0, 0, 0);
        }
        asm volatile("s_waitcnt vmcnt(0)" ::: "memory");
        __syncthreads();
    }

    #pragma unroll
    for (int fm = 0; fm < 2; ++fm)
        #pragma unroll
        for (int fn = 0; fn < 2; ++fn) {
            const int row0 = bm + wm * 32 + fm * 16 + kg * 4;
            const int col  = bn + wn * 32 + fn * 16 + arow;
            if (EPI == 0) {
                float* C = (float*)Cout;
                #pragma unroll
                for (int r = 0; r < 4; ++r)
                    C[(size_t)(row0 + r) * 512 + col] = acc[fm][fn][r];
            } else {
                unsigned short* C = (unsigned short*)Cout;   // C^T
                ushort4 pk;
                pk.x = f2bf(acc[fm][fn][0]);
                pk.y = f2bf(acc[fm][fn][1]);
                pk.z = f2bf(acc[fm][fn][2]);
                pk.w = f2bf(acc[fm][fn][3]);
                *(ushort4*)(&C[(size_t)col * 512 + row0]) = pk;
            }
        }
}

// ===== single cooperative kernel: r9's k1/k2/k3 as phases with grid.sync() =====
__global__ __launch_bounds__(256) void fused_all(
    const float* __restrict__ x, const float* __restrict__ w_attn,
    const float* __restrict__ w_proj,
    unsigned short* __restrict__ wv, unsigned short* __restrict__ wpT,
    unsigned short* __restrict__ wcT, unsigned short* __restrict__ s16,
    float* __restrict__ part, float* __restrict__ y)
{
    __shared__ __align__(16) unsigned short smem[2 * 2 * 4096];   // 32 KB, reused per phase
    cg::grid_group grid = cg::this_grid();
    const int bid = blockIdx.x, tid = threadIdx.x;

    // ---------- Phase 1: prep transpose / convert / partial sums (r9 k1) ----------
    if (bid < 64) {
        float (*ls)[65] = (float(*)[65])smem;                     // 64*65*4 = 16.6 KB
        const int m0 = (bid >> 3) * 64;
        const int j0 = (bid & 7) * 64;
        const int rr = tid >> 4;
        const int c4 = (tid & 15) * 4;
        #pragma unroll
        for (int i = 0; i < 4; ++i) {
            float4 v = *(const float4*)(w_proj + (size_t)(m0 + rr + 16 * i) * 512 + j0 + c4);
            ls[rr + 16 * i][c4 + 0] = v.x;
            ls[rr + 16 * i][c4 + 1] = v.y;
            ls[rr + 16 * i][c4 + 2] = v.z;
            ls[rr + 16 * i][c4 + 3] = v.w;
        }
        __syncthreads();
        const int c    = tid >> 2;
        const int mgrp = (tid & 3) * 16;
        #pragma unroll
        for (int u = 0; u < 4; ++u) {
            const int m = mgrp + u * 4;
            ushort4 o;
            o.x = f2bf(ls[m + 0][c]);
            o.y = f2bf(ls[m + 1][c]);
            o.z = f2bf(ls[m + 2][c]);
            o.w = f2bf(ls[m + 3][c]);
            *(ushort4*)(wpT + (size_t)(j0 + c) * 512 + m0 + m) = o;
        }
    } else if (bid < 128) {
        const int bb = bid - 64;
        #pragma unroll
        for (int i = 0; i < 4; ++i) {
            const int flat = bb * 1024 + i * 256 + tid;
            const int ir = flat >> 7;
            const int m4 = (flat & 127) * 4;
            float4 v = *(const float4*)(w_attn + (size_t)ir * 1536 + 1024 + m4);
            ushort4 o;
            o.x = f2bf(v.x); o.y = f2bf(v.y); o.z = f2bf(v.z); o.w = f2bf(v.w);
            *(ushort4*)(wv + (size_t)ir * 512 + m4) = o;
        }
    } else if (bid < 384) {
        const int bx = bid - 128;
        const int b  = bx >> 7;
        const int ch = (bx >> 1) & 63;
        const int j  = (bx & 1) * 256 + tid;
        const float* p = x + ((size_t)b * 2048 + ch * 32) * 512 + j;
        float s = 0.f;
        #pragma unroll 8
        for (int t = 0; t < 32; ++t) s += p[(size_t)t * 512];
        part[((size_t)b * 64 + ch) * 512 + j] = s;
    }

    grid.sync();

    // ---------- Phase 2: small GEMM + finalize (r9 k2) ----------
    if (bid < 64) {
        gemm_tile<1>(wv, wpT, wcT, smem, (bid >> 3) * 64, (bid & 7) * 64);
    } else if (bid < 320) {
        const int bx = bid - 64;
        const int b  = bx >> 7;
        const int ch = (bx >> 1) & 63;
        const int j  = (bx & 1) * 256 + tid;
        float run = 0.f;
        #pragma unroll 8
        for (int cc = 0; cc < 63; ++cc) {
            float v = part[((size_t)b * 64 + cc) * 512 + j];
            run += (cc < ch) ? v : 0.f;
        }
        const float*    p = x   + ((size_t)b * 2048 + ch * 32) * 512 + j;
        unsigned short* q = s16 + ((size_t)b * 2048 + ch * 32) * 512 + j;
        #pragma unroll 8
        for (int t = 0; t < 32; ++t) {
            run += p[(size_t)t * 512];
            q[(size_t)t * 512] = f2bf(run * (1.0f / (float)(ch * 32 + t + 1)));
        }
    }

    grid.sync();

    // ---------- Phase 3: big GEMM (r9 k3), XCD-chunked swizzle ----------
    {
        const int xcd = bid & 7;
        const int idx = bid >> 3;
        const int vy  = xcd * 8 + (idx >> 3);
        const int vx  = idx & 7;
        gemm_tile<0>(s16, wcT, y, smem, vy * 64, vx * 64);
    }
}

extern "C" void kernel_launch(void* const* d_in, const int* in_sizes, int n_in,
                              void* d_out, int out_size, void* d_ws, size_t ws_size,
                              hipStream_t stream)
{
    const float* x      = (const float*)d_in[0];   // (2,2048,512)
    const float* w_attn = (const float*)d_in[1];   // (512,1536); V = cols [1024,1536)
    const float* w_proj = (const float*)d_in[2];   // (512,512)
    float* y = (float*)d_out;

    unsigned short* wv  = (unsigned short*)d_ws;       // [512][512] bf16
    unsigned short* wpT = wv  + 512 * 512;             // [512][512] bf16 (w_proj^T)
    unsigned short* wcT = wpT + 512 * 512;             // [512][512] bf16 ((wv@wp)^T)
    unsigned short* s16 = wcT + 512 * 512;             // [4096][512] bf16
    float* part = (float*)(s16 + (size_t)4096 * 512);  // [2][64][512] f32

    void* args[] = { (void*)&x, (void*)&w_attn, (void*)&w_proj,
                     (void*)&wv, (void*)&wpT, (void*)&wcT,
                     (void*)&s16, (void*)&part, (void*)&y };
    hipLaunchCooperativeKernel((const void*)fused_all, dim3(512), dim3(256),
                               args, 0, stream);
}

// Round 12
// 24.728 us; speedup vs baseline: 5.8992x; 5.8992x over previous
//
#include <hip/hip_runtime.h>

typedef __bf16 bf16x8 __attribute__((ext_vector_type(8)));
typedef float  f32x4  __attribute__((ext_vector_type(4)));

__device__ __forceinline__ unsigned short f2bf(float f) {
    unsigned int u = __float_as_uint(f);
    u += 0x7FFF + ((u >> 16) & 1);          // RNE
    return (unsigned short)(u >> 16);
}

#define GLD_LDS16(gptr, lptr) \
    __builtin_amdgcn_global_load_lds((const __attribute__((address_space(1))) void*)(gptr), \
                                     (__attribute__((address_space(3))) void*)(lptr), 16, 0, 0)

// ---- 64x64-tile bf16 GEMM body, BK=128, 2-deep prefetch + counted vmcnt.
// C[m][n] = sum_k A[m][k]*Bt[n][k], K=512, ld=512.
// EPI=0: Cout=float[M][512] row-major. EPI=1: Cout=bf16 [512][512] transposed (C^T).
// lds: 2 bufs x (A 8192 + B 8192) ushorts = 64 KB.
template<int EPI>
__device__ __forceinline__ void gemm_tile(const unsigned short* __restrict__ A,
                                          const unsigned short* __restrict__ Bt,
                                          void* __restrict__ Cout,
                                          unsigned short* lds,
                                          int bm, int bn)
{
    const int tid  = threadIdx.x;
    const int lane = tid & 63;
    const int w    = tid >> 6;
    const int wm   = w >> 1, wn = w & 1;
    const int arow = lane & 15;
    const int kg   = lane >> 4;

    // staging: tile row-major [64][128] bf16 = [64 rows][16 chunks of 16B].
    // instruction i covers rows i*16 + (tid>>4); linear LDS dest (wave-uniform base).
    // source chunk pre-swizzled with the same involution used on reads: c ^ (row&15).
    const int srow   = tid >> 4;                 // row within 16-row group (= w*4 + lane>>4)
    const int schunk = (tid & 15) ^ srow;        // inverse-swizzle on SOURCE
    const unsigned short* gA = A  + (size_t)(bm + srow) * 512 + schunk * 8;
    const unsigned short* gB = Bt + (size_t)(bn + srow) * 512 + schunk * 8;

    auto stage = [&](int buf, int kt) {          // 8 gld_lds per wave per call
        unsigned short* la = lds + buf * 16384;
        unsigned short* lb = la + 8192;
        const int k0 = kt * 128;
        #pragma unroll
        for (int i = 0; i < 4; ++i) {
            GLD_LDS16(gA + (size_t)(i * 16) * 512 + k0, la + i * 2048 + w * 512);
            GLD_LDS16(gB + (size_t)(i * 16) * 512 + k0, lb + i * 2048 + w * 512);
        }
    };

    // fragment read byte-offsets (row stride 256B, chunk XOR row&15 == arow)
    int offA[2][4], offB[2][4];
    #pragma unroll
    for (int f = 0; f < 2; ++f)
        #pragma unroll
        for (int kk = 0; kk < 4; ++kk) {
            offA[f][kk] = (wm * 32 + f * 16 + arow) * 256 + (((kk * 4 + kg) ^ arow) << 4);
            offB[f][kk] = (wn * 32 + f * 16 + arow) * 256 + (((kk * 4 + kg) ^ arow) << 4);
        }

    stage(0, 0);
    stage(1, 1);                                  // 16 outstanding per wave

    f32x4 acc[2][2] = {};
    #pragma unroll
    for (int kt = 0; kt < 4; ++kt) {
        const int buf = kt & 1;
        if (kt < 3) asm volatile("s_waitcnt vmcnt(8)" ::: "memory");   // kt landed, kt+1 in flight
        else        asm volatile("s_waitcnt vmcnt(0)" ::: "memory");
        __builtin_amdgcn_s_barrier();             // all waves' tile-kt data visible
        const char* la = (const char*)(lds + buf * 16384);
        const char* lb = la + 16384;
        #pragma unroll
        for (int kk = 0; kk < 4; ++kk) {
            bf16x8 a0 = *(const bf16x8*)(la + offA[0][kk]);
            bf16x8 a1 = *(const bf16x8*)(la + offA[1][kk]);
            bf16x8 b0 = *(const bf16x8*)(lb + offB[0][kk]);
            bf16x8 b1 = *(const bf16x8*)(lb + offB[1][kk]);
            acc[0][0] = __builtin_amdgcn_mfma_f32_16x16x32_bf16(a0, b0, acc[0][0], 0, 0, 0);
            acc[0][1] = __builtin_amdgcn_mfma_f32_16x16x32_bf16(a0, b1, acc[0][1], 0, 0, 0);
            acc[1][0] = __builtin_amdgcn_mfma_f32_16x16x32_bf16(a1, b0, acc[1][0], 0, 0, 0);
            acc[1][1] = __builtin_amdgcn_mfma_f32_16x16x32_bf16(a1, b1, acc[1][1], 0, 0, 0);
        }
        // compiler guarantees lgkmcnt drained for the last MFMA's operands;
        // barrier then makes it safe to overwrite this buf.
        __builtin_amdgcn_s_barrier();
        if (kt < 2) stage(buf, kt + 2);
    }

    #pragma unroll
    for (int fm = 0; fm < 2; ++fm)
        #pragma unroll
        for (int fn = 0; fn < 2; ++fn) {
            const int row0 = bm + wm * 32 + fm * 16 + kg * 4;
            const int col  = bn + wn * 32 + fn * 16 + arow;
            if (EPI == 0) {
                float* C = (float*)Cout;
                #pragma unroll
                for (int r = 0; r < 4; ++r)
                    C[(size_t)(row0 + r) * 512 + col] = acc[fm][fn][r];
            } else {
                unsigned short* C = (unsigned short*)Cout;   // C^T
                ushort4 pk;
                pk.x = f2bf(acc[fm][fn][0]);
                pk.y = f2bf(acc[fm][fn][1]);
                pk.z = f2bf(acc[fm][fn][2]);
                pk.w = f2bf(acc[fm][fn][3]);
                *(ushort4*)(&C[(size_t)col * 512 + row0]) = pk;
            }
        }
}

// K1: blocks [0,64)   : LDS-tiled transpose w_proj -> wpT bf16
//     blocks [64,128) : w_attn V-slice -> wv bf16
//     blocks [128,384): partial_sums of x into part
__global__ __launch_bounds__(256) void k1_prep_partial(
    const float* __restrict__ x, const float* __restrict__ w_attn,
    const float* __restrict__ w_proj,
    unsigned short* __restrict__ wv, unsigned short* __restrict__ wpT,
    float* __restrict__ part)
{
    __shared__ float ls[64][65];
    const int bid = blockIdx.x, tid = threadIdx.x;

    if (bid < 64) {
        const int m0 = (bid >> 3) * 64;       // row block of w_proj
        const int j0 = (bid & 7) * 64;        // col block
        const int rr = tid >> 4;              // 0..15
        const int c4 = (tid & 15) * 4;
        #pragma unroll
        for (int i = 0; i < 4; ++i) {
            float4 v = *(const float4*)(w_proj + (size_t)(m0 + rr + 16 * i) * 512 + j0 + c4);
            ls[rr + 16 * i][c4 + 0] = v.x;
            ls[rr + 16 * i][c4 + 1] = v.y;
            ls[rr + 16 * i][c4 + 2] = v.z;
            ls[rr + 16 * i][c4 + 3] = v.w;
        }
        __syncthreads();
        const int c    = tid >> 2;            // 0..63 (j within tile)
        const int mgrp = (tid & 3) * 16;
        #pragma unroll
        for (int u = 0; u < 4; ++u) {
            const int m = mgrp + u * 4;
            ushort4 o;
            o.x = f2bf(ls[m + 0][c]);
            o.y = f2bf(ls[m + 1][c]);
            o.z = f2bf(ls[m + 2][c]);
            o.w = f2bf(ls[m + 3][c]);
            *(ushort4*)(wpT + (size_t)(j0 + c) * 512 + m0 + m) = o;
        }
    } else if (bid < 128) {
        const int bb = bid - 64;
        #pragma unroll
        for (int i = 0; i < 4; ++i) {
            const int flat = bb * 1024 + i * 256 + tid;   // float4 index in [512][128]
            const int ir = flat >> 7;
            const int m4 = (flat & 127) * 4;
            float4 v = *(const float4*)(w_attn + (size_t)ir * 1536 + 1024 + m4);
            ushort4 o;
            o.x = f2bf(v.x); o.y = f2bf(v.y); o.z = f2bf(v.z); o.w = f2bf(v.w);
            *(ushort4*)(wv + (size_t)ir * 512 + m4) = o;
        }
    } else {
        const int bx = bid - 128;             // 0..255
        const int b  = bx >> 7;
        const int ch = (bx >> 1) & 63;
        const int j  = (bx & 1) * 256 + tid;
        const float* p = x + ((size_t)b * 2048 + ch * 32) * 512 + j;
        float s = 0.f;
        #pragma unroll 8
        for (int t = 0; t < 32; ++t) s += p[(size_t)t * 512];
        part[((size_t)b * 64 + ch) * 512 + j] = s;
    }
}

// K2: blocks [0,64)  : small GEMM wcT = (wv @ wp)^T
//     blocks [64,320): finalize (masked fixed-trip prefix, fully pipelined) -> s16
__global__ __launch_bounds__(256) void k2_smallgemm_finalize(
    const float* __restrict__ x,
    const unsigned short* __restrict__ wv, const unsigned short* __restrict__ wpT,
    const float* __restrict__ part,
    unsigned short* __restrict__ wcT, unsigned short* __restrict__ s16)
{
    __shared__ __align__(16) unsigned short lds[2 * 16384];   // 64 KB
    const int bid = blockIdx.x, tid = threadIdx.x;

    if (bid < 64) {
        gemm_tile<1>(wv, wpT, wcT, lds, (bid >> 3) * 64, (bid & 7) * 64);
    } else {
        const int bx = bid - 64;              // 0..255
        const int b  = bx >> 7;
        const int ch = (bx >> 1) & 63;
        const int j  = (bx & 1) * 256 + tid;
        float run = 0.f;
        #pragma unroll 8
        for (int cc = 0; cc < 63; ++cc) {
            float v = part[((size_t)b * 64 + cc) * 512 + j];
            run += (cc < ch) ? v : 0.f;
        }
        const float*    p = x   + ((size_t)b * 2048 + ch * 32) * 512 + j;
        unsigned short* q = s16 + ((size_t)b * 2048 + ch * 32) * 512 + j;
        #pragma unroll 8
        for (int t = 0; t < 32; ++t) {
            run += p[(size_t)t * 512];
            q[(size_t)t * 512] = f2bf(run * (1.0f / (float)(ch * 32 + t + 1)));
        }
    }
}

// K3: y = s16 @ wcT^T  (4096x512x512), XCD-chunked swizzle over 512 blocks
__global__ __launch_bounds__(256) void k3_biggemm(
    const unsigned short* __restrict__ s16,
    const unsigned short* __restrict__ wcT,
    float* __restrict__ y)
{
    __shared__ __align__(16) unsigned short lds[2 * 16384];   // 64 KB
    const int bid  = blockIdx.x;            // 0..511
    const int xcd  = bid & 7;
    const int idx  = bid >> 3;              // 0..63
    const int vy   = xcd * 8 + (idx >> 3);  // m-tile 0..63
    const int vx   = idx & 7;               // n-tile 0..7
    gemm_tile<0>(s16, wcT, y, lds, vy * 64, vx * 64);
}

extern "C" void kernel_launch(void* const* d_in, const int* in_sizes, int n_in,
                              void* d_out, int out_size, void* d_ws, size_t ws_size,
                              hipStream_t stream)
{
    const float* x      = (const float*)d_in[0];   // (2,2048,512)
    const float* w_attn = (const float*)d_in[1];   // (512,1536); V = cols [1024,1536)
    const float* w_proj = (const float*)d_in[2];   // (512,512)
    float* y = (float*)d_out;

    unsigned short* wv  = (unsigned short*)d_ws;       // [512][512] bf16
    unsigned short* wpT = wv  + 512 * 512;             // [512][512] bf16 (w_proj^T)
    unsigned short* wcT = wpT + 512 * 512;             // [512][512] bf16 ((wv@wp)^T)
    unsigned short* s16 = wcT + 512 * 512;             // [4096][512] bf16
    float* part = (float*)(s16 + (size_t)4096 * 512);  // [2][64][512] f32

    k1_prep_partial<<<384, 256, 0, stream>>>(x, w_attn, w_proj, wv, wpT, part);
    k2_smallgemm_finalize<<<320, 256, 0, stream>>>(x, wv, wpT, part, wcT, s16);
    k3_biggemm<<<512, 256, 0, stream>>>(s16, wcT, y);
}